// Round 2
// baseline (98.921 us; speedup 1.0000x reference)
//
#include <hip/hip_runtime.h>
#include <math.h>

#define NSTEP 69
#define OBS 8
#define NSTATE 11   // state 3 of the reference's 12 is dead (feeds nothing, unread)

namespace {

constexpr float kDT = 60.0f / 69.0f;

struct ETab { float lo[NSTEP]; float mid[NSTEP]; float hi[NSTEP]; };

constexpr float interp_e(float t) {
    constexpr float DTm[16] = {0.f,2.f,4.f,6.f,8.f,10.f,12.f,14.f,16.f,18.f,20.f,25.f,30.f,40.f,50.f,60.f};
    constexpr float EP[16]  = {0.01713f,0.145f,0.2442f,0.7659f,1.0f,0.8605f,0.7829f,0.5705f,
                               0.6217f,0.331f,0.3388f,0.3116f,0.05062f,0.02504f,0.01163f,0.01163f};
    if (t >= 60.0f) return EP[15];
    if (t <= 0.0f)  return EP[0];
    int k = 0;
    for (int m = 0; m < 15; m++) if (t >= DTm[m]) k = m;
    float u = (t - DTm[k]) / (DTm[k + 1] - DTm[k]);
    return EP[k] + u * (EP[k + 1] - EP[k]);
}

constexpr ETab make_etab() {
    ETab e{};
    for (int s = 0; s < NSTEP; s++) {
        float t0 = (float)s * kDT;
        e.lo[s]  = interp_e(t0);
        e.mid[s] = interp_e(t0 + 0.5f * kDT);
        e.hi[s]  = interp_e(t0 + kDT);
    }
    return e;
}

} // namespace

__device__ constexpr ETab ETAB = make_etab();

__device__ __forceinline__ void deriv(const float (&xs)[NSTATE], float k1, float k2,
                                      float r, float E, float (&d)[NSTATE]) {
    float a  = k1 * xs[0] * E;
    float sq = xs[1] * xs[1];
    d[0] = fmaf(k2, xs[10], -a);
    d[1] = a - sq;
    d[2] = fmaf(-k2, xs[2], sq);
    #pragma unroll
    for (int i = 3; i < NSTATE; i++) d[i] = r * (xs[i - 1] - xs[i]);
}

__global__ __launch_bounds__(256) void stats5_kernel(
    const float* __restrict__ params,
    const float* __restrict__ design,
    const float* __restrict__ noise,
    float* __restrict__ out,
    int B)
{
    int b = blockIdx.x * blockDim.x + threadIdx.x;
    if (b >= B) return;

    // ---- design readout coefficients: computed per-thread from uniform loads,
    // forced into SGPRs via readfirstlane of a lane-uniform value (no LDS).
    int   ij[OBS]; float wj[OBS], w1j[OBS];
    #pragma unroll
    for (int j = 0; j < OBS; j++) {
        float pos = design[j] * (1.0f / kDT);
        int i = (int)pos;                      // pos >= 0, trunc == floor
        i = i < 0 ? 0 : (i > NSTEP - 1 ? NSTEP - 1 : i);
        float w = pos - (float)i;
        ij[j]  = __builtin_amdgcn_readfirstlane(i);
        int wb = __builtin_amdgcn_readfirstlane(__float_as_int(w));
        wj[j]  = __int_as_float(wb);
        w1j[j] = 1.0f - wj[j];
    }

    // ---- parameter transform: shift + Phi(p)*scale, Phi(x) = 0.5*erfc(-x/sqrt2)
    float p0 = params[3 * b], p1 = params[3 * b + 1], p2 = params[3 * b + 2];
    const float INV_SQRT2 = 0.7071067811865476f;
    float k1  = fmaf(0.5f * erfcf(-p0 * INV_SQRT2), 2.5f,  0.5f);
    float k2  = fmaf(0.5f * erfcf(-p1 * INV_SQRT2), 0.15f, 0.05f);
    float tau = fmaf(0.5f * erfcf(-p2 * INV_SQRT2), 6.0f,  4.0f);
    float r = 8.0f / tau;

    float o1[OBS], o2[OBS];
    #pragma unroll
    for (int j = 0; j < OBS; j++) { o1[j] = 0.f; o2[j] = 0.f; }

    // state layout: [0..2] = x1,x2,x3 ; [3..9] = q1..q7 ; [10] = out
    float x[NSTATE];
    #pragma unroll
    for (int i = 0; i < NSTATE; i++) x[i] = 0.f;
    x[0] = 3.71f;

    // emit at time index 0
    {
        float y1 = 0.33f * (x[1] + x[2]);
        float y2 = 0.26f * (x[0] + x[1] + x[2]);
        #pragma unroll
        for (int j = 0; j < OBS; j++) {
            if (0 == ij[j]) { o1[j] += w1j[j] * y1; o2[j] += w1j[j] * y2; }
        }
    }

    for (int s = 0; s < NSTEP; s++) {
        float ea = ETAB.lo[s], eb = ETAB.mid[s], ec = ETAB.hi[s];
        float d1[NSTATE], d2[NSTATE], d3[NSTATE], d4[NSTATE], xs[NSTATE];
        deriv(x, k1, k2, r, ea, d1);
        #pragma unroll
        for (int i = 0; i < NSTATE; i++) xs[i] = fmaf(0.5f * kDT, d1[i], x[i]);
        deriv(xs, k1, k2, r, eb, d2);
        #pragma unroll
        for (int i = 0; i < NSTATE; i++) xs[i] = fmaf(0.5f * kDT, d2[i], x[i]);
        deriv(xs, k1, k2, r, eb, d3);
        #pragma unroll
        for (int i = 0; i < NSTATE; i++) xs[i] = fmaf(kDT, d3[i], x[i]);
        deriv(xs, k1, k2, r, ec, d4);
        #pragma unroll
        for (int i = 0; i < NSTATE; i++)
            x[i] = fmaf(kDT * (1.0f / 6.0f), d1[i] + 2.0f * (d2[i] + d3[i]) + d4[i], x[i]);

        // emit at time index s+1
        float y1 = 0.33f * (x[1] + x[2]);
        float y2 = 0.26f * (x[0] + x[1] + x[2]);
        int ti = s + 1;
        #pragma unroll
        for (int j = 0; j < OBS; j++) {
            if (ti == ij[j])     { o1[j] += w1j[j] * y1; o2[j] += w1j[j] * y2; }
            if (ti == ij[j] + 1) { o1[j] += wj[j]  * y1; o2[j] += wj[j]  * y2; }
        }
    }

    long long base = (long long)b * 16;
    long long nb   = (long long)B * 16;
    #pragma unroll
    for (int j = 0; j < OBS; j++) {
        float t1 = o1[j], t2 = o2[j];
        out[base + j]          = t1;
        out[base + 8 + j]      = t2;
        out[nb + base + j]     = fmaf(0.01f, noise[base + j],     t1);
        out[nb + base + 8 + j] = fmaf(0.01f, noise[base + 8 + j], t2);
    }
}

extern "C" void kernel_launch(void* const* d_in, const int* in_sizes, int n_in,
                              void* d_out, int out_size, void* d_ws, size_t ws_size,
                              hipStream_t stream) {
    const float* params = (const float*)d_in[0];
    const float* design = (const float*)d_in[1];
    const float* noise  = (const float*)d_in[2];
    float* out = (float*)d_out;
    int B = in_sizes[0] / 3;
    int block = 256;
    int grid = (B + block - 1) / block;
    stats5_kernel<<<grid, block, 0, stream>>>(params, design, noise, out, B);
}

// Round 3
// 87.971 us; speedup vs baseline: 1.1245x; 1.1245x over previous
//
#include <hip/hip_runtime.h>
#include <math.h>

#define NSTEP 69
#define OBS 8

typedef float f32x2 __attribute__((ext_vector_type(2)));

namespace {

constexpr float kDT = 60.0f / 69.0f;

struct ETab { float lo[NSTEP]; float mid[NSTEP]; float hi[NSTEP]; };

constexpr float interp_e(float t) {
    constexpr float DTm[16] = {0.f,2.f,4.f,6.f,8.f,10.f,12.f,14.f,16.f,18.f,20.f,25.f,30.f,40.f,50.f,60.f};
    constexpr float EP[16]  = {0.01713f,0.145f,0.2442f,0.7659f,1.0f,0.8605f,0.7829f,0.5705f,
                               0.6217f,0.331f,0.3388f,0.3116f,0.05062f,0.02504f,0.01163f,0.01163f};
    if (t >= 60.0f) return EP[15];
    if (t <= 0.0f)  return EP[0];
    int k = 0;
    for (int m = 0; m < 15; m++) if (t >= DTm[m]) k = m;
    float u = (t - DTm[k]) / (DTm[k + 1] - DTm[k]);
    return EP[k] + u * (EP[k + 1] - EP[k]);
}

constexpr ETab make_etab() {
    ETab e{};
    for (int s = 0; s < NSTEP; s++) {
        float t0 = (float)s * kDT;
        e.lo[s]  = interp_e(t0);
        e.mid[s] = interp_e(t0 + 0.5f * kDT);
        e.hi[s]  = interp_e(t0 + kDT);
    }
    return e;
}

} // namespace

__device__ constexpr ETab ETAB = make_etab();

// State: specials x0,x1,x2 ; q-chain x2 -> q1..q7 -> out packed as pairs
// P0=(q1,q5) P1=(q2,q6) P2=(q3,q7) P3=(q4,out).  prev(P1)=P0, prev(P2)=P1,
// prev(P3)=P2, prev(P0)=(x2, P3.x) — packed-friendly (v_pk_*_f32).
struct St { float x0, x1, x2; f32x2 P0, P1, P2, P3; };
struct Dv { float d0, d1, d2; f32x2 D0, D1, D2, D3; };

__device__ __forceinline__ Dv deriv(const St& s, float k1E, float k2, f32x2 r2) {
    Dv d;
    float a  = k1E * s.x0;
    float sq = s.x1 * s.x1;
    d.d0 = fmaf(k2, s.P3.y, -a);
    d.d1 = a - sq;
    d.d2 = fmaf(-k2, s.x2, sq);
    f32x2 s0; s0.x = s.x2; s0.y = s.P3.x;
    d.D0 = r2 * (s0   - s.P0);
    d.D1 = r2 * (s.P0 - s.P1);
    d.D2 = r2 * (s.P1 - s.P2);
    d.D3 = r2 * (s.P2 - s.P3);
    return d;
}

__device__ __forceinline__ St axpy(const St& x, float c, const Dv& d) {
    St y; f32x2 c2 = {c, c};
    y.x0 = fmaf(c, d.d0, x.x0);
    y.x1 = fmaf(c, d.d1, x.x1);
    y.x2 = fmaf(c, d.d2, x.x2);
    y.P0 = c2 * d.D0 + x.P0;   // -ffp-contract=fast -> v_pk_fma_f32
    y.P1 = c2 * d.D1 + x.P1;
    y.P2 = c2 * d.D2 + x.P2;
    y.P3 = c2 * d.D3 + x.P3;
    return y;
}

__global__ __launch_bounds__(256) void stats5_kernel(
    const float* __restrict__ params,
    const float* __restrict__ design,
    const float* __restrict__ noise,
    float* __restrict__ out,
    int B)
{
    int b = blockIdx.x * blockDim.x + threadIdx.x;
    if (b >= B) return;

    // ---- design readout: per-thread from uniform loads, forced to SGPR.
    int ij[OBS], ij1[OBS]; float wj[OBS], w1j[OBS];
    #pragma unroll
    for (int j = 0; j < OBS; j++) {
        float pos = design[j] * (1.0f / kDT);
        int i = (int)pos;
        i = i < 0 ? 0 : (i > NSTEP - 1 ? NSTEP - 1 : i);
        float w = pos - (float)i;
        ij[j]  = __builtin_amdgcn_readfirstlane(i);
        ij1[j] = ij[j] + 1;
        int wb = __builtin_amdgcn_readfirstlane(__float_as_int(w));
        wj[j]  = __int_as_float(wb);
        w1j[j] = 1.0f - wj[j];
    }

    // 70-bit "a tap fires at this step" scalar mask
    unsigned long long m_lo = 0ull, m_hi = 0ull;
    #pragma unroll
    for (int j = 0; j < OBS; j++) {
        if (ij[j]  < 64) m_lo |= 1ull << ij[j];  else m_hi |= 1ull << (ij[j]  - 64);
        if (ij1[j] < 64) m_lo |= 1ull << ij1[j]; else m_hi |= 1ull << (ij1[j] - 64);
    }

    // ---- parameter transform: shift + Phi(p)*scale, Phi(x)=0.5*erfc(-x/sqrt2)
    float p0 = params[3 * b], p1 = params[3 * b + 1], p2 = params[3 * b + 2];
    const float INV_SQRT2 = 0.7071067811865476f;
    float k1  = fmaf(0.5f * erfcf(-p0 * INV_SQRT2), 2.5f,  0.5f);
    float k2  = fmaf(0.5f * erfcf(-p1 * INV_SQRT2), 0.15f, 0.05f);
    float tau = fmaf(0.5f * erfcf(-p2 * INV_SQRT2), 6.0f,  4.0f);
    float r = 8.0f / tau;
    f32x2 r2 = {r, r};

    // tap records (registers, statically indexed)
    float a12[OBS], a0[OBS], b12[OBS], b0[OBS];
    #pragma unroll
    for (int j = 0; j < OBS; j++) { a12[j] = 0.f; a0[j] = 0.f; b12[j] = 0.f; b0[j] = 0.f; }

    St x;
    x.x0 = 3.71f; x.x1 = 0.f; x.x2 = 0.f;
    x.P0 = (f32x2){0.f, 0.f}; x.P1 = x.P0; x.P2 = x.P0; x.P3 = x.P0;

    // record at ti = 0 (only lo-taps possible)
    if (m_lo & 1ull) {
        #pragma unroll
        for (int j = 0; j < OBS; j++)
            if (ij[j] == 0) { a12[j] = 0.f; a0[j] = 3.71f; }
    }

    for (int s = 0; s < NSTEP; s++) {
        float ea = ETAB.lo[s], eb = ETAB.mid[s], ec = ETAB.hi[s];
        float k1a = k1 * ea, k1b = k1 * eb, k1c = k1 * ec;

        Dv d1 = deriv(x, k1a, k2, r2);
        St t  = axpy(x, 0.5f * kDT, d1);
        Dv d2 = deriv(t, k1b, k2, r2);
        t     = axpy(x, 0.5f * kDT, d2);
        Dv d3 = deriv(t, k1b, k2, r2);
        t     = axpy(x, kDT, d3);
        Dv d4 = deriv(t, k1c, k2, r2);

        const float c6 = kDT * (1.0f / 6.0f);
        {
            float u;
            u = fmaf(2.0f, d2.d0 + d3.d0, d1.d0 + d4.d0); x.x0 = fmaf(c6, u, x.x0);
            u = fmaf(2.0f, d2.d1 + d3.d1, d1.d1 + d4.d1); x.x1 = fmaf(c6, u, x.x1);
            u = fmaf(2.0f, d2.d2 + d3.d2, d1.d2 + d4.d2); x.x2 = fmaf(c6, u, x.x2);
            f32x2 two = {2.0f, 2.0f}, c62 = {c6, c6}, v;
            v = two * (d2.D0 + d3.D0) + (d1.D0 + d4.D0); x.P0 = c62 * v + x.P0;
            v = two * (d2.D1 + d3.D1) + (d1.D1 + d4.D1); x.P1 = c62 * v + x.P1;
            v = two * (d2.D2 + d3.D2) + (d1.D2 + d4.D2); x.P2 = c62 * v + x.P2;
            v = two * (d2.D3 + d3.D3) + (d1.D3 + d4.D3); x.P3 = c62 * v + x.P3;
        }

        int ti = s + 1;
        bool any = (ti < 64) ? ((m_lo >> ti) & 1ull) : ((m_hi >> (ti - 64)) & 1ull);
        if (any) {
            float s12 = x.x1 + x.x2;
            #pragma unroll
            for (int j = 0; j < OBS; j++) {
                if (ti == ij[j])  { a12[j] = s12; a0[j] = x.x0; }
                if (ti == ij1[j]) { b12[j] = s12; b0[j] = x.x0; }
            }
        }
    }

    float o1[OBS], o2[OBS];
    #pragma unroll
    for (int j = 0; j < OBS; j++) {
        o1[j] = 0.33f * fmaf(w1j[j], a12[j], wj[j] * b12[j]);
        o2[j] = 0.26f * fmaf(w1j[j], a0[j] + a12[j], wj[j] * (b0[j] + b12[j]));
    }

    long long base = (long long)b * 16;
    long long nb   = (long long)B * 16;
    float4* outv = (float4*)(out + base);
    float4* outn = (float4*)(out + nb + base);
    const float4* nz = (const float4*)(noise + base);

    float4 v0 = make_float4(o1[0], o1[1], o1[2], o1[3]);
    float4 v1 = make_float4(o1[4], o1[5], o1[6], o1[7]);
    float4 v2 = make_float4(o2[0], o2[1], o2[2], o2[3]);
    float4 v3 = make_float4(o2[4], o2[5], o2[6], o2[7]);
    outv[0] = v0; outv[1] = v1; outv[2] = v2; outv[3] = v3;

    float4 n0 = nz[0], n1 = nz[1], n2 = nz[2], n3 = nz[3];
    outn[0] = make_float4(fmaf(0.01f, n0.x, v0.x), fmaf(0.01f, n0.y, v0.y),
                          fmaf(0.01f, n0.z, v0.z), fmaf(0.01f, n0.w, v0.w));
    outn[1] = make_float4(fmaf(0.01f, n1.x, v1.x), fmaf(0.01f, n1.y, v1.y),
                          fmaf(0.01f, n1.z, v1.z), fmaf(0.01f, n1.w, v1.w));
    outn[2] = make_float4(fmaf(0.01f, n2.x, v2.x), fmaf(0.01f, n2.y, v2.y),
                          fmaf(0.01f, n2.z, v2.z), fmaf(0.01f, n2.w, v2.w));
    outn[3] = make_float4(fmaf(0.01f, n3.x, v3.x), fmaf(0.01f, n3.y, v3.y),
                          fmaf(0.01f, n3.z, v3.z), fmaf(0.01f, n3.w, v3.w));
}

extern "C" void kernel_launch(void* const* d_in, const int* in_sizes, int n_in,
                              void* d_out, int out_size, void* d_ws, size_t ws_size,
                              hipStream_t stream) {
    const float* params = (const float*)d_in[0];
    const float* design = (const float*)d_in[1];
    const float* noise  = (const float*)d_in[2];
    float* out = (float*)d_out;
    int B = in_sizes[0] / 3;
    int block = 256;
    int grid = (B + block - 1) / block;
    stats5_kernel<<<grid, block, 0, stream>>>(params, design, noise, out, B);
}

// Round 4
// 85.691 us; speedup vs baseline: 1.1544x; 1.0266x over previous
//
#include <hip/hip_runtime.h>
#include <math.h>

#define NSTEP 69
#define OBS 8

typedef float f32x2 __attribute__((ext_vector_type(2)));

namespace {

constexpr float kDT = 60.0f / 69.0f;

struct ETab { float lo[NSTEP]; float mid[NSTEP]; float hi[NSTEP]; };

constexpr float interp_e(float t) {
    constexpr float DTm[16] = {0.f,2.f,4.f,6.f,8.f,10.f,12.f,14.f,16.f,18.f,20.f,25.f,30.f,40.f,50.f,60.f};
    constexpr float EP[16]  = {0.01713f,0.145f,0.2442f,0.7659f,1.0f,0.8605f,0.7829f,0.5705f,
                               0.6217f,0.331f,0.3388f,0.3116f,0.05062f,0.02504f,0.01163f,0.01163f};
    if (t >= 60.0f) return EP[15];
    if (t <= 0.0f)  return EP[0];
    int k = 0;
    for (int m = 0; m < 15; m++) if (t >= DTm[m]) k = m;
    float u = (t - DTm[k]) / (DTm[k + 1] - DTm[k]);
    return EP[k] + u * (EP[k + 1] - EP[k]);
}

constexpr ETab make_etab() {
    ETab e{};
    for (int s = 0; s < NSTEP; s++) {
        float t0 = (float)s * kDT;
        e.lo[s]  = interp_e(t0);
        e.mid[s] = interp_e(t0 + 0.5f * kDT);
        e.hi[s]  = interp_e(t0 + kDT);
    }
    return e;
}

constexpr ETab ETAB = make_etab();   // folded to literals under full unroll

} // namespace

// State: specials x0,x1,x2 ; q-chain x2 -> q1..q7 -> out packed as pairs
// P0=(q1,q5) P1=(q2,q6) P2=(q3,q7) P3=(q4,out).  prev(P1)=P0, prev(P2)=P1,
// prev(P3)=P2, prev(P0)=(x2, P3.x) — packed-friendly (v_pk_*_f32).
struct St { float x0, x1, x2; f32x2 P0, P1, P2, P3; };
struct Dv { float d0, d1, d2; f32x2 D0, D1, D2, D3; };

__device__ __forceinline__ Dv deriv(const St& s, float k1E, float k2, f32x2 r2) {
    Dv d;
    float a  = k1E * s.x0;
    float sq = s.x1 * s.x1;
    d.d0 = fmaf(k2, s.P3.y, -a);
    d.d1 = a - sq;
    d.d2 = fmaf(-k2, s.x2, sq);
    f32x2 s0; s0.x = s.x2; s0.y = s.P3.x;
    d.D0 = r2 * (s0   - s.P0);
    d.D1 = r2 * (s.P0 - s.P1);
    d.D2 = r2 * (s.P1 - s.P2);
    d.D3 = r2 * (s.P2 - s.P3);
    return d;
}

__device__ __forceinline__ St axpy(const St& x, float c, const Dv& d) {
    St y; f32x2 c2 = {c, c};
    y.x0 = fmaf(c, d.d0, x.x0);
    y.x1 = fmaf(c, d.d1, x.x1);
    y.x2 = fmaf(c, d.d2, x.x2);
    y.P0 = c2 * d.D0 + x.P0;
    y.P1 = c2 * d.D1 + x.P1;
    y.P2 = c2 * d.D2 + x.P2;
    y.P3 = c2 * d.D3 + x.P3;
    return y;
}

__global__ __launch_bounds__(256) void stats5_kernel(
    const float* __restrict__ params,
    const float* __restrict__ design,
    const float* __restrict__ noise,
    float* __restrict__ out,
    int B)
{
    int b = blockIdx.x * blockDim.x + threadIdx.x;
    if (b >= B) return;

    // ---- design readout: per-thread from uniform loads, forced to SGPR.
    int ij[OBS], ij1[OBS]; float wj[OBS], w1j[OBS];
    #pragma unroll
    for (int j = 0; j < OBS; j++) {
        float pos = design[j] * (1.0f / kDT);
        int i = (int)pos;
        i = i < 0 ? 0 : (i > NSTEP - 1 ? NSTEP - 1 : i);
        float w = pos - (float)i;
        ij[j]  = __builtin_amdgcn_readfirstlane(i);
        ij1[j] = ij[j] + 1;
        int wb = __builtin_amdgcn_readfirstlane(__float_as_int(w));
        wj[j]  = __int_as_float(wb);
        w1j[j] = 1.0f - wj[j];
    }

    // 70-bit "a tap fires at this step" scalar mask
    unsigned long long m_lo = 0ull, m_hi = 0ull;
    #pragma unroll
    for (int j = 0; j < OBS; j++) {
        if (ij[j]  < 64) m_lo |= 1ull << ij[j];  else m_hi |= 1ull << (ij[j]  - 64);
        if (ij1[j] < 64) m_lo |= 1ull << ij1[j]; else m_hi |= 1ull << (ij1[j] - 64);
    }

    // ---- parameter transform: shift + Phi(p)*scale, Phi(x)=0.5*erfc(-x/sqrt2)
    float p0 = params[3 * b], p1 = params[3 * b + 1], p2 = params[3 * b + 2];
    const float INV_SQRT2 = 0.7071067811865476f;
    float k1  = fmaf(0.5f * erfcf(-p0 * INV_SQRT2), 2.5f,  0.5f);
    float k2  = fmaf(0.5f * erfcf(-p1 * INV_SQRT2), 0.15f, 0.05f);
    float tau = fmaf(0.5f * erfcf(-p2 * INV_SQRT2), 6.0f,  4.0f);
    float r = 8.0f / tau;
    f32x2 r2 = {r, r};

    // tap records (registers, statically indexed)
    float a12[OBS], a0[OBS], b12[OBS], b0[OBS];
    #pragma unroll
    for (int j = 0; j < OBS; j++) { a12[j] = 0.f; a0[j] = 0.f; b12[j] = 0.f; b0[j] = 0.f; }

    St x;
    x.x0 = 3.71f; x.x1 = 0.f; x.x2 = 0.f;
    x.P0 = (f32x2){0.f, 0.f}; x.P1 = x.P0; x.P2 = x.P0; x.P3 = x.P0;

    // record at ti = 0 (only lo-taps possible)
    if (m_lo & 1ull) {
        #pragma unroll
        for (int j = 0; j < OBS; j++)
            if (ij[j] == 0) { a12[j] = 0.f; a0[j] = 3.71f; }
    }

    #pragma unroll
    for (int s = 0; s < NSTEP; s++) {
        // compile-time constants under full unroll — zero loads in the body
        const float ea = ETAB.lo[s], eb = ETAB.mid[s], ec = ETAB.hi[s];
        float k1a = k1 * ea, k1b = k1 * eb, k1c = k1 * ec;

        Dv d1 = deriv(x, k1a, k2, r2);
        St t  = axpy(x, 0.5f * kDT, d1);
        Dv d2 = deriv(t, k1b, k2, r2);
        t     = axpy(x, 0.5f * kDT, d2);
        Dv d3 = deriv(t, k1b, k2, r2);
        t     = axpy(x, kDT, d3);
        Dv d4 = deriv(t, k1c, k2, r2);

        const float c6 = kDT * (1.0f / 6.0f);
        {
            float u;
            u = fmaf(2.0f, d2.d0 + d3.d0, d1.d0 + d4.d0); x.x0 = fmaf(c6, u, x.x0);
            u = fmaf(2.0f, d2.d1 + d3.d1, d1.d1 + d4.d1); x.x1 = fmaf(c6, u, x.x1);
            u = fmaf(2.0f, d2.d2 + d3.d2, d1.d2 + d4.d2); x.x2 = fmaf(c6, u, x.x2);
            f32x2 two = {2.0f, 2.0f}, c62 = {c6, c6}, v;
            v = two * (d2.D0 + d3.D0) + (d1.D0 + d4.D0); x.P0 = c62 * v + x.P0;
            v = two * (d2.D1 + d3.D1) + (d1.D1 + d4.D1); x.P1 = c62 * v + x.P1;
            v = two * (d2.D2 + d3.D2) + (d1.D2 + d4.D2); x.P2 = c62 * v + x.P2;
            v = two * (d2.D3 + d3.D3) + (d1.D3 + d4.D3); x.P3 = c62 * v + x.P3;
        }

        const int ti = s + 1;   // compile-time: bit-select below folds to one SALU test
        bool any = (ti < 64) ? ((m_lo >> ti) & 1ull) : ((m_hi >> (ti - 64)) & 1ull);
        if (any) {
            float s12 = x.x1 + x.x2;
            #pragma unroll
            for (int j = 0; j < OBS; j++) {
                if (ti == ij[j])  { a12[j] = s12; a0[j] = x.x0; }
                if (ti == ij1[j]) { b12[j] = s12; b0[j] = x.x0; }
            }
        }
    }

    float o1[OBS], o2[OBS];
    #pragma unroll
    for (int j = 0; j < OBS; j++) {
        o1[j] = 0.33f * fmaf(w1j[j], a12[j], wj[j] * b12[j]);
        o2[j] = 0.26f * fmaf(w1j[j], a0[j] + a12[j], wj[j] * (b0[j] + b12[j]));
    }

    long long base = (long long)b * 16;
    long long nb   = (long long)B * 16;
    float4* outv = (float4*)(out + base);
    float4* outn = (float4*)(out + nb + base);
    const float4* nz = (const float4*)(noise + base);

    float4 v0 = make_float4(o1[0], o1[1], o1[2], o1[3]);
    float4 v1 = make_float4(o1[4], o1[5], o1[6], o1[7]);
    float4 v2 = make_float4(o2[0], o2[1], o2[2], o2[3]);
    float4 v3 = make_float4(o2[4], o2[5], o2[6], o2[7]);
    outv[0] = v0; outv[1] = v1; outv[2] = v2; outv[3] = v3;

    float4 n0 = nz[0], n1 = nz[1], n2 = nz[2], n3 = nz[3];
    outn[0] = make_float4(fmaf(0.01f, n0.x, v0.x), fmaf(0.01f, n0.y, v0.y),
                          fmaf(0.01f, n0.z, v0.z), fmaf(0.01f, n0.w, v0.w));
    outn[1] = make_float4(fmaf(0.01f, n1.x, v1.x), fmaf(0.01f, n1.y, v1.y),
                          fmaf(0.01f, n1.z, v1.z), fmaf(0.01f, n1.w, v1.w));
    outn[2] = make_float4(fmaf(0.01f, n2.x, v2.x), fmaf(0.01f, n2.y, v2.y),
                          fmaf(0.01f, n2.z, v2.z), fmaf(0.01f, n2.w, v2.w));
    outn[3] = make_float4(fmaf(0.01f, n3.x, v3.x), fmaf(0.01f, n3.y, v3.y),
                          fmaf(0.01f, n3.z, v3.z), fmaf(0.01f, n3.w, v3.w));
}

extern "C" void kernel_launch(void* const* d_in, const int* in_sizes, int n_in,
                              void* d_out, int out_size, void* d_ws, size_t ws_size,
                              hipStream_t stream) {
    const float* params = (const float*)d_in[0];
    const float* design = (const float*)d_in[1];
    const float* noise  = (const float*)d_in[2];
    float* out = (float*)d_out;
    int B = in_sizes[0] / 3;
    int block = 256;
    int grid = (B + block - 1) / block;
    stats5_kernel<<<grid, block, 0, stream>>>(params, design, noise, out, B);
}